// Round 5
// baseline (159.069 us; speedup 1.0000x reference)
//
#include <hip/hip_runtime.h>

#define E_ 56
#define DIM_ 512
#define V_ 256
#define F_ 504       // E_*9
#define NROWS 65536  // B*L

typedef float  vf4 __attribute__((ext_vector_type(4)));

__device__ __forceinline__ float sigmoidf_(float v) { return 1.0f / (1.0f + expf(-v)); }
__device__ __forceinline__ float bf_lo_(unsigned int u) {
  return __uint_as_float(u << 16);
}
__device__ __forceinline__ float bf_hi_(unsigned int u) {
  return __uint_as_float(u & 0xFFFF0000u);
}
__device__ __forceinline__ float bf2f_(unsigned short u) {
  return __uint_as_float(((unsigned int)u) << 16);
}
__device__ __forceinline__ unsigned short f2bf_(float f) {  // round-nearest-even
  unsigned int b = __float_as_uint(f);
  b += 0x7FFFu + ((b >> 16) & 1u);
  return (unsigned short)(b >> 16);
}

// ---- transposes: PW2[p][d][e] = proj_w[d][e*9+p];  Ct[c][k][e] = conv_w[e][c*9+k]
__global__ __launch_bounds__(256) void k_trans(
    const float* __restrict__ proj_w,   // [512][504]
    const float* __restrict__ conv_w,   // [56][504]  (e, c*9+k)
    float* __restrict__ PW2,            // [9][512][56]
    float* __restrict__ Ct)             // [56][9][56]
{
  int idx = blockIdx.x * 256 + threadIdx.x;
  if (idx < 9 * DIM_ * E_) {            // 258048
    int p = idx / (DIM_ * E_);
    int r = idx - p * (DIM_ * E_);
    int d = r / E_;
    int e = r - d * E_;
    PW2[idx] = proj_w[d * F_ + e * 9 + p];
  } else {
    int j = idx - 9 * DIM_ * E_;        // 28224 = 56*9*56
    if (j >= E_ * 9 * E_) return;
    int c = j / (9 * E_);
    int r = j - c * (9 * E_);
    int k = r / E_;
    int e = r - k * E_;
    Ct[j] = conv_w[e * F_ + c * 9 + k];
  }
}

// ---------------- Weff fold: conv + gate + projection -> one linear map ----
// Wt layout: [q][c][d], d contiguous.
__global__ __launch_bounds__(256) void k_weff2(
    const float* __restrict__ proj_w,   // [512][504]
    const float* __restrict__ PW2,      // [9][512][56]
    const float* __restrict__ Ct,       // [56][9][56]
    const float* __restrict__ alpha,    // [9]
    float* __restrict__ Wt)             // [9][56][512] f32
{
  int idx = blockIdx.x * 256 + threadIdx.x;   // 512*504 threads
  int d = idx / F_;
  int f = idx - d * F_;
  int c = f / 9;
  int q = f - c * 9;
  int qi = q / 3, qj = q - qi * 3;
  float acc = sigmoidf_(alpha[q]) * proj_w[d * F_ + c * 9 + q];
  #pragma unroll
  for (int p = 0; p < 9; ++p) {
    int pi = p / 3, pj = p - pi * 3;
    int ki = qi - pi + 1, kj = qj - pj + 1;
    if (ki < 0 || ki > 2 || kj < 0 || kj > 2) continue;
    const vf4* A = (const vf4*)(PW2 + (p * DIM_ + d) * E_);
    const vf4* B = (const vf4*)(Ct + (c * 9 + (ki * 3 + kj)) * E_);
    vf4 sv = {0.f, 0.f, 0.f, 0.f};
    #pragma unroll
    for (int e4 = 0; e4 < E_ / 4; ++e4)
      sv += A[e4] * B[e4];
    float s = sv.x + sv.y + sv.z + sv.w;
    acc += (1.f - sigmoidf_(alpha[p])) * s;
  }
  Wt[(size_t)(q * E_ + c) * DIM_ + d] = acc;
}

__global__ __launch_bounds__(256) void k_beff(
    const float* __restrict__ proj_w,
    const float* __restrict__ conv_b,
    const float* __restrict__ proj_b,
    const float* __restrict__ alpha,
    float* __restrict__ beff)           // [512]
{
  int d = blockIdx.x * 256 + threadIdx.x;
  if (d >= DIM_) return;
  const float* pr = proj_w + d * F_;
  float acc = proj_b[d];
  for (int p = 0; p < 9; ++p) {
    float s = 0.f;
    for (int e = 0; e < E_; ++e) s += pr[e * 9 + p] * conv_b[e];
    acc += (1.f - sigmoidf_(alpha[p])) * s;
  }
  beff[d] = acc;
}

// T[q][t][d] = sum_c emb[t][c] * Wt[q][c][d];  8 tokens per block.
__global__ __launch_bounds__(256) void k_tab8(
    const float* __restrict__ emb,      // [256][56]
    const float* __restrict__ Wt,       // [9][56][512] f32
    unsigned short* __restrict__ T)     // [9][256][512] bf16
{
  int q  = blockIdx.x >> 5;            // 9
  int t0 = (blockIdx.x & 31) * 8;      // 32 groups of 8 tokens
  int d0 = 2 * threadIdx.x;
  float a0[8], a1[8];
  #pragma unroll
  for (int j = 0; j < 8; ++j) { a0[j] = 0.f; a1[j] = 0.f; }
  for (int c = 0; c < E_; ++c) {
    float2 w = *(const float2*)(Wt + (size_t)(q * E_ + c) * DIM_ + d0);
    #pragma unroll
    for (int j = 0; j < 8; ++j) {
      float ev = emb[(t0 + j) * E_ + c];   // uniform -> s_load
      a0[j] += ev * w.x;
      a1[j] += ev * w.y;
    }
  }
  #pragma unroll
  for (int j = 0; j < 8; ++j) {
    size_t o = (size_t)((q << 8) + t0 + j) * DIM_ + d0;
    unsigned int u = (unsigned int)f2bf_(a0[j]) | ((unsigned int)f2bf_(a1[j]) << 16);
    *(unsigned int*)(T + o) = u;
  }
}

// Shared LayerNorm tail helpers ---------------------------------------------
__device__ __forceinline__ void ln_reduce_(const float a[8], float& mu, float& rstd) {
  float s = 0.f, ss = 0.f;
  #pragma unroll
  for (int j = 0; j < 8; ++j) { s += a[j]; ss += a[j] * a[j]; }
  #pragma unroll
  for (int off = 32; off > 0; off >>= 1) {
    s  += __shfl_xor(s, off, 64);
    ss += __shfl_xor(ss, off, 64);
  }
  mu = s * (1.0f / 512.0f);
  float var = ss * (1.0f / 512.0f) - mu * mu;
  rstd = rsqrtf(var + 1e-5f);
}

// One wave per row: 9 bf16 gathers (all in flight), then unpack+LN+NT store.
__global__ __launch_bounds__(256) void k_main_bf(
    const int*            __restrict__ x,     // [65536][9]
    const unsigned short* __restrict__ T,     // [9][256][512] bf16
    const float* __restrict__ beff,
    const float* __restrict__ gamma,
    const float* __restrict__ beta,
    float* __restrict__ out)                  // [65536][512]
{
  int gid = blockIdx.x * 256 + threadIdx.x;
  int row = gid >> 6;
  int lane = threadIdx.x & 63;
  int tok = 0;
  if (lane < 9) tok = x[row * 9 + lane];

  uint4 u[9];
  #pragma unroll
  for (int q = 0; q < 9; ++q) {
    int t = __shfl(tok, q, 64);
    u[q] = *((const uint4*)(T + (size_t)((q << 8) + t) * DIM_) + lane);
  }

  const float4* b4 = (const float4*)beff;
  float4 B0 = b4[2 * lane], B1 = b4[2 * lane + 1];
  float a[8] = {B0.x, B0.y, B0.z, B0.w, B1.x, B1.y, B1.z, B1.w};

  #pragma unroll
  for (int q = 0; q < 9; ++q) {
    a[0] += bf_lo_(u[q].x); a[1] += bf_hi_(u[q].x);
    a[2] += bf_lo_(u[q].y); a[3] += bf_hi_(u[q].y);
    a[4] += bf_lo_(u[q].z); a[5] += bf_hi_(u[q].z);
    a[6] += bf_lo_(u[q].w); a[7] += bf_hi_(u[q].w);
  }

  float mu, rstd;
  ln_reduce_(a, mu, rstd);

  const float4* g4  = (const float4*)gamma;
  const float4* be4 = (const float4*)beta;
  float4 G0 = g4[2 * lane], G1 = g4[2 * lane + 1];
  float4 P0 = be4[2 * lane], P1 = be4[2 * lane + 1];

  vf4 o0, o1;
  o0.x = (a[0] - mu) * rstd * G0.x + P0.x;
  o0.y = (a[1] - mu) * rstd * G0.y + P0.y;
  o0.z = (a[2] - mu) * rstd * G0.z + P0.z;
  o0.w = (a[3] - mu) * rstd * G0.w + P0.w;
  o1.x = (a[4] - mu) * rstd * G1.x + P1.x;
  o1.y = (a[5] - mu) * rstd * G1.y + P1.y;
  o1.z = (a[6] - mu) * rstd * G1.z + P1.z;
  o1.w = (a[7] - mu) * rstd * G1.w + P1.w;

  vf4* o4 = (vf4*)(out + (size_t)row * DIM_ + lane * 8);
  __builtin_nontemporal_store(o0, o4);
  __builtin_nontemporal_store(o1, o4 + 1);
}

// ----------------- fallback (tiny ws): no T table --------------------------
__global__ __launch_bounds__(256) void k_weff_bf(
    const float* __restrict__ proj_w,
    const float* __restrict__ conv_w,
    const float* __restrict__ alpha,
    unsigned short* __restrict__ Wt)
{
  int idx = blockIdx.x * 256 + threadIdx.x;
  int d = idx / F_;
  int f = idx - d * F_;
  int c = f / 9;
  int q = f - c * 9;
  int qi = q / 3, qj = q - qi * 3;
  const float* pr = proj_w + d * F_;
  float acc = sigmoidf_(alpha[q]) * pr[c * 9 + q];
  for (int pi = 0; pi < 3; ++pi) {
    for (int pj = 0; pj < 3; ++pj) {
      int ki = qi - pi + 1, kj = qj - pj + 1;
      if (ki < 0 || ki > 2 || kj < 0 || kj > 2) continue;
      int p = pi * 3 + pj;
      const float* cwp = conv_w + c * 9 + (ki * 3 + kj);
      const float* prp = pr + p;
      float s = 0.f;
      #pragma unroll 8
      for (int e = 0; e < E_; ++e)
        s += prp[e * 9] * cwp[e * F_];
      acc += (1.f - sigmoidf_(alpha[p])) * s;
    }
  }
  Wt[(size_t)(q * E_ + c) * DIM_ + d] = f2bf_(acc);
}

__global__ __launch_bounds__(256) void k_init(
    const float* __restrict__ beff, float* __restrict__ out)
{
  int idx = blockIdx.x * 256 + threadIdx.x;
  ((float4*)out)[idx] = ((const float4*)beff)[idx & 127];
}

__global__ __launch_bounds__(256) void k_accq(
    const int* __restrict__ x,
    const float* __restrict__ emb,
    const unsigned short* __restrict__ Wt,
    float* __restrict__ out, int q)
{
  const int tid = threadIdx.x;
  const int d = blockIdx.y * 256 + tid;
  const int row0 = blockIdx.x * 512;
  const unsigned short* wq = Wt + (size_t)(q * E_) * DIM_ + d;

  for (int rb = 0; rb < 512; rb += 8) {
    int tv[8]; float a[8];
    #pragma unroll
    for (int j = 0; j < 8; ++j) {
      tv[j] = x[(size_t)(row0 + rb + j) * 9 + q];
      a[j] = 0.f;
    }
    for (int c = 0; c < E_; ++c) {
      float w = bf2f_(wq[(size_t)c * DIM_]);
      #pragma unroll
      for (int j = 0; j < 8; ++j)
        a[j] += emb[tv[j] * E_ + c] * w;
    }
    #pragma unroll
    for (int j = 0; j < 8; ++j) {
      size_t o = (size_t)(row0 + rb + j) * DIM_ + d;
      out[o] += a[j];
    }
  }
}

__global__ __launch_bounds__(256) void k_ln(
    const float* __restrict__ gamma, const float* __restrict__ beta,
    float* __restrict__ out)
{
  int gid = blockIdx.x * 256 + threadIdx.x;
  int row = gid >> 6;
  int lane = threadIdx.x & 63;
  float* op = out + (size_t)row * DIM_ + lane * 8;
  float4 A0 = *(float4*)op, A1 = *(float4*)(op + 4);
  float a[8] = {A0.x, A0.y, A0.z, A0.w, A1.x, A1.y, A1.z, A1.w};
  float mu, rstd;
  ln_reduce_(a, mu, rstd);
  const float4* g4  = (const float4*)gamma;
  const float4* be4 = (const float4*)beta;
  float4 G0 = g4[2 * lane], G1 = g4[2 * lane + 1];
  float4 P0 = be4[2 * lane], P1 = be4[2 * lane + 1];
  float4 o0, o1;
  o0.x = (a[0] - mu) * rstd * G0.x + P0.x;
  o0.y = (a[1] - mu) * rstd * G0.y + P0.y;
  o0.z = (a[2] - mu) * rstd * G0.z + P0.z;
  o0.w = (a[3] - mu) * rstd * G0.w + P0.w;
  o1.x = (a[4] - mu) * rstd * G1.x + P1.x;
  o1.y = (a[5] - mu) * rstd * G1.y + P1.y;
  o1.z = (a[6] - mu) * rstd * G1.z + P1.z;
  o1.w = (a[7] - mu) * rstd * G1.w + P1.w;
  *(float4*)op = o0;
  *(float4*)(op + 4) = o1;
}

extern "C" void kernel_launch(void* const* d_in, const int* in_sizes, int n_in,
                              void* d_out, int out_size, void* d_ws, size_t ws_size,
                              hipStream_t stream) {
  const int*   x      = (const int*)  d_in[0];
  const float* emb    = (const float*)d_in[1];
  const float* alpha  = (const float*)d_in[2];
  const float* conv_w = (const float*)d_in[3];
  const float* conv_b = (const float*)d_in[4];
  const float* proj_w = (const float*)d_in[5];
  const float* proj_b = (const float*)d_in[6];
  const float* gamma  = (const float*)d_in[7];
  const float* beta   = (const float*)d_in[8];
  float* out = (float*)d_out;

  float* beff = (float*)d_ws;
  char* wsbase = (char*)d_ws;

  const size_t OFF_WT  = 2048;
  const size_t OFF_T   = OFF_WT + (size_t)9 * E_ * DIM_ * 4;   // 1,034,240
  const size_t OFF_PW2 = OFF_T  + (size_t)9 * V_ * DIM_ * 2;   // 3,393,536
  const size_t OFF_CT  = OFF_PW2 + (size_t)9 * DIM_ * E_ * 4;  // 4,425,728
  const size_t needMain = OFF_CT + (size_t)E_ * 9 * E_ * 4;    // 4,538,624

  hipLaunchKernelGGL(k_beff, dim3(2), dim3(256), 0, stream,
                     proj_w, conv_b, proj_b, alpha, beff);

  if (ws_size >= needMain) {
    float* Wt  = (float*)(wsbase + OFF_WT);
    unsigned short* T = (unsigned short*)(wsbase + OFF_T);
    float* PW2 = (float*)(wsbase + OFF_PW2);
    float* Ct  = (float*)(wsbase + OFF_CT);
    hipLaunchKernelGGL(k_trans, dim3(1119), dim3(256), 0, stream,
                       proj_w, conv_w, PW2, Ct);
    hipLaunchKernelGGL(k_weff2, dim3((DIM_ * F_) / 256), dim3(256), 0, stream,
                       proj_w, PW2, Ct, alpha, Wt);
    hipLaunchKernelGGL(k_tab8, dim3(9 * 32), dim3(256), 0, stream,
                       emb, Wt, T);
    hipLaunchKernelGGL(k_main_bf, dim3(NROWS / 4), dim3(256), 0, stream,
                       x, T, beff, gamma, beta, out);
  } else {
    unsigned short* Wt = (unsigned short*)(wsbase + 2048);
    hipLaunchKernelGGL(k_weff_bf, dim3((DIM_ * F_) / 256), dim3(256), 0, stream,
                       proj_w, conv_w, alpha, Wt);
    hipLaunchKernelGGL(k_init, dim3((NROWS * DIM_ / 4) / 256), dim3(256), 0, stream,
                       beff, out);
    for (int q = 0; q < 9; ++q)
      hipLaunchKernelGGL(k_accq, dim3(128, 2), dim3(256), 0, stream,
                         x, emb, Wt, out, q);
    hipLaunchKernelGGL(k_ln, dim3(NROWS / 4), dim3(256), 0, stream,
                       gamma, beta, out);
  }
}

// Round 6
// 105.001 us; speedup vs baseline: 1.5149x; 1.5149x over previous
//
#include <hip/hip_runtime.h>

#define E_ 56
#define DIM_ 512
#define V_ 256
#define F_ 504       // E_*9
#define NROWS 65536  // B*L

typedef float  vf4 __attribute__((ext_vector_type(4)));

__device__ __forceinline__ float sigmoidf_(float v) { return 1.0f / (1.0f + expf(-v)); }
__device__ __forceinline__ float bf_lo_(unsigned int u) {
  return __uint_as_float(u << 16);
}
__device__ __forceinline__ float bf_hi_(unsigned int u) {
  return __uint_as_float(u & 0xFFFF0000u);
}
__device__ __forceinline__ float bf2f_(unsigned short u) {
  return __uint_as_float(((unsigned int)u) << 16);
}
__device__ __forceinline__ unsigned short f2bf_(float f) {  // round-nearest-even
  unsigned int b = __float_as_uint(f);
  b += 0x7FFFu + ((b >> 16) & 1u);
  return (unsigned short)(b >> 16);
}

// ---- transposes: PW2[p][d][e] = proj_w[d][e*9+p];  Ct[c][k][e] = conv_w[e][c*9+k]
__global__ __launch_bounds__(256) void k_trans(
    const float* __restrict__ proj_w,   // [512][504]
    const float* __restrict__ conv_w,   // [56][504]  (e, c*9+k)
    float* __restrict__ PW2,            // [9][512][56]
    float* __restrict__ Ct)             // [56][9][56]
{
  int idx = blockIdx.x * 256 + threadIdx.x;
  if (idx < 9 * DIM_ * E_) {            // 258048
    int p = idx / (DIM_ * E_);
    int r = idx - p * (DIM_ * E_);
    int d = r / E_;
    int e = r - d * E_;
    PW2[idx] = proj_w[d * F_ + e * 9 + p];
  } else {
    int j = idx - 9 * DIM_ * E_;        // 28224 = 56*9*56
    if (j >= E_ * 9 * E_) return;
    int c = j / (9 * E_);
    int r = j - c * (9 * E_);
    int k = r / E_;
    int e = r - k * E_;
    Ct[j] = conv_w[e * F_ + c * 9 + k];
  }
}

// ---------------- Weff fold: conv + gate + projection -> one linear map ----
__global__ __launch_bounds__(256) void k_weff2(
    const float* __restrict__ proj_w,   // [512][504]
    const float* __restrict__ PW2,      // [9][512][56]
    const float* __restrict__ Ct,       // [56][9][56]
    const float* __restrict__ alpha,    // [9]
    float* __restrict__ Wt)             // [9][56][512] f32
{
  int idx = blockIdx.x * 256 + threadIdx.x;   // 512*504 threads
  int d = idx / F_;
  int f = idx - d * F_;
  int c = f / 9;
  int q = f - c * 9;
  int qi = q / 3, qj = q - qi * 3;
  float acc = sigmoidf_(alpha[q]) * proj_w[d * F_ + c * 9 + q];
  #pragma unroll
  for (int p = 0; p < 9; ++p) {
    int pi = p / 3, pj = p - pi * 3;
    int ki = qi - pi + 1, kj = qj - pj + 1;
    if (ki < 0 || ki > 2 || kj < 0 || kj > 2) continue;
    const vf4* A = (const vf4*)(PW2 + (p * DIM_ + d) * E_);
    const vf4* B = (const vf4*)(Ct + (c * 9 + (ki * 3 + kj)) * E_);
    vf4 sv = {0.f, 0.f, 0.f, 0.f};
    #pragma unroll
    for (int e4 = 0; e4 < E_ / 4; ++e4)
      sv += A[e4] * B[e4];
    float s = sv.x + sv.y + sv.z + sv.w;
    acc += (1.f - sigmoidf_(alpha[p])) * s;
  }
  Wt[(size_t)(q * E_ + c) * DIM_ + d] = acc;
}

// beff: one wave per d, lane-parallel over e, butterfly reduce. 512 blocks.
__global__ __launch_bounds__(64) void k_beff_w(
    const float* __restrict__ proj_w,
    const float* __restrict__ conv_b,
    const float* __restrict__ proj_b,
    const float* __restrict__ alpha,
    float* __restrict__ beff)           // [512]
{
  int d = blockIdx.x;
  int lane = threadIdx.x;
  const float* pr = proj_w + d * F_;
  float acc = 0.f;
  #pragma unroll
  for (int p = 0; p < 9; ++p) {
    float v = 0.f;
    if (lane < E_) v = pr[lane * 9 + p] * conv_b[lane];
    #pragma unroll
    for (int off = 32; off > 0; off >>= 1) v += __shfl_xor(v, off, 64);
    acc += (1.f - sigmoidf_(alpha[p])) * v;
  }
  if (lane == 0) beff[d] = proj_b[d] + acc;
}

// T[q][t][d] = sum_c emb[t][c] * Wt[q][c][d];  8 tokens per block.
__global__ __launch_bounds__(256) void k_tab8(
    const float* __restrict__ emb,      // [256][56]
    const float* __restrict__ Wt,       // [9][56][512] f32
    unsigned short* __restrict__ T)     // [9][256][512] bf16
{
  int q  = blockIdx.x >> 5;            // 9
  int t0 = (blockIdx.x & 31) * 8;      // 32 groups of 8 tokens
  int d0 = 2 * threadIdx.x;
  float a0[8], a1[8];
  #pragma unroll
  for (int j = 0; j < 8; ++j) { a0[j] = 0.f; a1[j] = 0.f; }
  for (int c = 0; c < E_; ++c) {
    float2 w = *(const float2*)(Wt + (size_t)(q * E_ + c) * DIM_ + d0);
    #pragma unroll
    for (int j = 0; j < 8; ++j) {
      float ev = emb[(t0 + j) * E_ + c];   // uniform -> scalar load
      a0[j] += ev * w.x;
      a1[j] += ev * w.y;
    }
  }
  #pragma unroll
  for (int j = 0; j < 8; ++j) {
    size_t o = (size_t)((q << 8) + t0 + j) * DIM_ + d0;
    unsigned int u = (unsigned int)f2bf_(a0[j]) | ((unsigned int)f2bf_(a1[j]) << 16);
    *(unsigned int*)(T + o) = u;
  }
}

// Shared LayerNorm tail helpers ---------------------------------------------
__device__ __forceinline__ void ln_reduce_(const float a[8], float& mu, float& rstd) {
  float s = 0.f, ss = 0.f;
  #pragma unroll
  for (int j = 0; j < 8; ++j) { s += a[j]; ss += a[j] * a[j]; }
  #pragma unroll
  for (int off = 32; off > 0; off >>= 1) {
    s  += __shfl_xor(s, off, 64);
    ss += __shfl_xor(ss, off, 64);
  }
  mu = s * (1.0f / 512.0f);
  float var = ss * (1.0f / 512.0f) - mu * mu;
  rstd = rsqrtf(var + 1e-5f);
}

// One wave per row. row forced to SGPR; tokens via uniform (scalar) loads;
// 9 gathers issued back-to-back off SGPR bases; unpack+LN+NT store.
__global__ __launch_bounds__(256) void k_main_bf(
    const int*            __restrict__ x,     // [65536][9]
    const unsigned short* __restrict__ T,     // [9][256][512] bf16
    const float* __restrict__ beff,
    const float* __restrict__ gamma,
    const float* __restrict__ beta,
    float* __restrict__ out)                  // [65536][512]
{
  int row = __builtin_amdgcn_readfirstlane((blockIdx.x * 256 + threadIdx.x) >> 6);
  int lane = threadIdx.x & 63;
  const int* __restrict__ xr = x + row * 9;

  uint4 u[9];
  #pragma unroll
  for (int q = 0; q < 9; ++q) {
    int t = xr[q];                            // uniform address -> s_load
    u[q] = *((const uint4*)(T + (size_t)((q << 8) + t) * DIM_) + lane);
  }

  const float4* b4 = (const float4*)beff;
  float4 B0 = b4[2 * lane], B1 = b4[2 * lane + 1];
  float a[8] = {B0.x, B0.y, B0.z, B0.w, B1.x, B1.y, B1.z, B1.w};

  #pragma unroll
  for (int q = 0; q < 9; ++q) {
    a[0] += bf_lo_(u[q].x); a[1] += bf_hi_(u[q].x);
    a[2] += bf_lo_(u[q].y); a[3] += bf_hi_(u[q].y);
    a[4] += bf_lo_(u[q].z); a[5] += bf_hi_(u[q].z);
    a[6] += bf_lo_(u[q].w); a[7] += bf_hi_(u[q].w);
  }

  float mu, rstd;
  ln_reduce_(a, mu, rstd);

  const float4* g4  = (const float4*)gamma;
  const float4* be4 = (const float4*)beta;
  float4 G0 = g4[2 * lane], G1 = g4[2 * lane + 1];
  float4 P0 = be4[2 * lane], P1 = be4[2 * lane + 1];

  vf4 o0, o1;
  o0.x = (a[0] - mu) * rstd * G0.x + P0.x;
  o0.y = (a[1] - mu) * rstd * G0.y + P0.y;
  o0.z = (a[2] - mu) * rstd * G0.z + P0.z;
  o0.w = (a[3] - mu) * rstd * G0.w + P0.w;
  o1.x = (a[4] - mu) * rstd * G1.x + P1.x;
  o1.y = (a[5] - mu) * rstd * G1.y + P1.y;
  o1.z = (a[6] - mu) * rstd * G1.z + P1.z;
  o1.w = (a[7] - mu) * rstd * G1.w + P1.w;

  vf4* o4 = (vf4*)(out + (size_t)row * DIM_ + lane * 8);
  __builtin_nontemporal_store(o0, o4);
  __builtin_nontemporal_store(o1, o4 + 1);
}

// ----------------- fallback (tiny ws): no T table --------------------------
__global__ __launch_bounds__(256) void k_weff_bf(
    const float* __restrict__ proj_w,
    const float* __restrict__ conv_w,
    const float* __restrict__ alpha,
    unsigned short* __restrict__ Wt)
{
  int idx = blockIdx.x * 256 + threadIdx.x;
  int d = idx / F_;
  int f = idx - d * F_;
  int c = f / 9;
  int q = f - c * 9;
  int qi = q / 3, qj = q - qi * 3;
  const float* pr = proj_w + d * F_;
  float acc = sigmoidf_(alpha[q]) * pr[c * 9 + q];
  for (int pi = 0; pi < 3; ++pi) {
    for (int pj = 0; pj < 3; ++pj) {
      int ki = qi - pi + 1, kj = qj - pj + 1;
      if (ki < 0 || ki > 2 || kj < 0 || kj > 2) continue;
      int p = pi * 3 + pj;
      const float* cwp = conv_w + c * 9 + (ki * 3 + kj);
      const float* prp = pr + p;
      float s = 0.f;
      #pragma unroll 8
      for (int e = 0; e < E_; ++e)
        s += prp[e * 9] * cwp[e * F_];
      acc += (1.f - sigmoidf_(alpha[p])) * s;
    }
  }
  Wt[(size_t)(q * E_ + c) * DIM_ + d] = f2bf_(acc);
}

__global__ __launch_bounds__(256) void k_init(
    const float* __restrict__ beff, float* __restrict__ out)
{
  int idx = blockIdx.x * 256 + threadIdx.x;
  ((float4*)out)[idx] = ((const float4*)beff)[idx & 127];
}

__global__ __launch_bounds__(256) void k_accq(
    const int* __restrict__ x,
    const float* __restrict__ emb,
    const unsigned short* __restrict__ Wt,
    float* __restrict__ out, int q)
{
  const int tid = threadIdx.x;
  const int d = blockIdx.y * 256 + tid;
  const int row0 = blockIdx.x * 512;
  const unsigned short* wq = Wt + (size_t)(q * E_) * DIM_ + d;

  for (int rb = 0; rb < 512; rb += 8) {
    int tv[8]; float a[8];
    #pragma unroll
    for (int j = 0; j < 8; ++j) {
      tv[j] = x[(size_t)(row0 + rb + j) * 9 + q];
      a[j] = 0.f;
    }
    for (int c = 0; c < E_; ++c) {
      float w = bf2f_(wq[(size_t)c * DIM_]);
      #pragma unroll
      for (int j = 0; j < 8; ++j)
        a[j] += emb[tv[j] * E_ + c] * w;
    }
    #pragma unroll
    for (int j = 0; j < 8; ++j) {
      size_t o = (size_t)(row0 + rb + j) * DIM_ + d;
      out[o] += a[j];
    }
  }
}

__global__ __launch_bounds__(256) void k_ln(
    const float* __restrict__ gamma, const float* __restrict__ beta,
    float* __restrict__ out)
{
  int gid = blockIdx.x * 256 + threadIdx.x;
  int row = gid >> 6;
  int lane = threadIdx.x & 63;
  float* op = out + (size_t)row * DIM_ + lane * 8;
  float4 A0 = *(float4*)op, A1 = *(float4*)(op + 4);
  float a[8] = {A0.x, A0.y, A0.z, A0.w, A1.x, A1.y, A1.z, A1.w};
  float mu, rstd;
  ln_reduce_(a, mu, rstd);
  const float4* g4  = (const float4*)gamma;
  const float4* be4 = (const float4*)beta;
  float4 G0 = g4[2 * lane], G1 = g4[2 * lane + 1];
  float4 P0 = be4[2 * lane], P1 = be4[2 * lane + 1];
  float4 o0, o1;
  o0.x = (a[0] - mu) * rstd * G0.x + P0.x;
  o0.y = (a[1] - mu) * rstd * G0.y + P0.y;
  o0.z = (a[2] - mu) * rstd * G0.z + P0.z;
  o0.w = (a[3] - mu) * rstd * G0.w + P0.w;
  o1.x = (a[4] - mu) * rstd * G1.x + P1.x;
  o1.y = (a[5] - mu) * rstd * G1.y + P1.y;
  o1.z = (a[6] - mu) * rstd * G1.z + P1.z;
  o1.w = (a[7] - mu) * rstd * G1.w + P1.w;
  *(float4*)op = o0;
  *(float4*)(op + 4) = o1;
}

extern "C" void kernel_launch(void* const* d_in, const int* in_sizes, int n_in,
                              void* d_out, int out_size, void* d_ws, size_t ws_size,
                              hipStream_t stream) {
  const int*   x      = (const int*)  d_in[0];
  const float* emb    = (const float*)d_in[1];
  const float* alpha  = (const float*)d_in[2];
  const float* conv_w = (const float*)d_in[3];
  const float* conv_b = (const float*)d_in[4];
  const float* proj_w = (const float*)d_in[5];
  const float* proj_b = (const float*)d_in[6];
  const float* gamma  = (const float*)d_in[7];
  const float* beta   = (const float*)d_in[8];
  float* out = (float*)d_out;

  float* beff = (float*)d_ws;
  char* wsbase = (char*)d_ws;

  const size_t OFF_WT  = 2048;
  const size_t OFF_T   = OFF_WT + (size_t)9 * E_ * DIM_ * 4;   // 1,034,240
  const size_t OFF_PW2 = OFF_T  + (size_t)9 * V_ * DIM_ * 2;   // 3,393,536
  const size_t OFF_CT  = OFF_PW2 + (size_t)9 * DIM_ * E_ * 4;  // 4,425,728
  const size_t needMain = OFF_CT + (size_t)E_ * 9 * E_ * 4;    // 4,538,624

  hipLaunchKernelGGL(k_beff_w, dim3(DIM_), dim3(64), 0, stream,
                     proj_w, conv_b, proj_b, alpha, beff);

  if (ws_size >= needMain) {
    float* Wt  = (float*)(wsbase + OFF_WT);
    unsigned short* T = (unsigned short*)(wsbase + OFF_T);
    float* PW2 = (float*)(wsbase + OFF_PW2);
    float* Ct  = (float*)(wsbase + OFF_CT);
    hipLaunchKernelGGL(k_trans, dim3(1119), dim3(256), 0, stream,
                       proj_w, conv_w, PW2, Ct);
    hipLaunchKernelGGL(k_weff2, dim3((DIM_ * F_) / 256), dim3(256), 0, stream,
                       proj_w, PW2, Ct, alpha, Wt);
    hipLaunchKernelGGL(k_tab8, dim3(9 * 32), dim3(256), 0, stream,
                       emb, Wt, T);
    hipLaunchKernelGGL(k_main_bf, dim3(NROWS / 4), dim3(256), 0, stream,
                       x, T, beff, gamma, beta, out);
  } else {
    unsigned short* Wt = (unsigned short*)(wsbase + 2048);
    hipLaunchKernelGGL(k_weff_bf, dim3((DIM_ * F_) / 256), dim3(256), 0, stream,
                       proj_w, conv_w, alpha, Wt);
    hipLaunchKernelGGL(k_init, dim3((NROWS * DIM_ / 4) / 256), dim3(256), 0, stream,
                       beff, out);
    for (int q = 0; q < 9; ++q)
      hipLaunchKernelGGL(k_accq, dim3(128, 2), dim3(256), 0, stream,
                         x, emb, Wt, out, q);
    hipLaunchKernelGGL(k_ln, dim3(NROWS / 4), dim3(256), 0, stream,
                       gamma, beta, out);
  }
}